// Round 13
// baseline (3953.925 us; speedup 1.0000x reference)
//
#include <hip/hip_runtime.h>
#include <hip/hip_fp16.h>

#define N 8192
#define ITERS 50
#define ROWS 8      // rows per block (both paths)
#define NBLK 1024   // 256 CU x 4 blocks/CU, co-resident via launch_bounds(256,4)
#define NSLOT 8     // nsq partial-sum slots (reduce single-line RMW contention)
#define SPAD 32     // floats per nsq slot (128 B line)
#define CPAD 32     // ints per barrier slot (128 B line)

typedef unsigned int uint32;

__device__ __forceinline__ uint32 pack2h(float x, float y) {
    __half2 p = __float22half2_rn(make_float2(x, y));
    return *reinterpret_cast<uint32*>(&p);
}

__device__ __forceinline__ float2 h2f(uint32 u) {
    __half2 h = *reinterpret_cast<__half2*>(&u);
    return __half22float2(h);
}

// agent-scope accessors (coherence point; used ONLY for tiny cross-block data)
__device__ __forceinline__ float ldf_agent(const float* p) {
    return __hip_atomic_load(p, __ATOMIC_RELAXED, __HIP_MEMORY_SCOPE_AGENT);
}
__device__ __forceinline__ void stf_agent(float* p, float v) {
    __hip_atomic_store(p, v, __ATOMIC_RELAXED, __HIP_MEMORY_SCOPE_AGENT);
}

// relaxed grid barrier (r12-proven): cross-block data is already at the
// coherence point before the closing __syncthreads of the producer phase
// (s_waitcnt vmcnt(0) precedes s_barrier), so no release/acquire needed.
__device__ __forceinline__ void gbar(int* cnt, int slot) {
    __syncthreads();
    if (threadIdx.x == 0) {
        __hip_atomic_fetch_add(&cnt[slot * CPAD], 1, __ATOMIC_RELAXED,
                               __HIP_MEMORY_SCOPE_AGENT);
        while (__hip_atomic_load(&cnt[slot * CPAD], __ATOMIC_RELAXED,
                                 __HIP_MEMORY_SCOPE_AGENT) < NBLK)
            __builtin_amdgcn_s_sleep(8);
    }
    __syncthreads();
}

// 8-row epilogue: wave reduce -> LDS -> rows written via agent stores,
// block's sum(y^2) added into its nsq slot (8 slots cut RMW serialization).
__device__ __forceinline__ void epi8(float (&acc)[8], int t, int row0, float s,
                                     float* vout, float* nsq_slot) {
#pragma unroll
    for (int r = 0; r < 8; ++r) {
        float a = acc[r];
        for (int off = 32; off > 0; off >>= 1) a += __shfl_down(a, off, 64);
        acc[r] = a;
    }
    __shared__ float part[4][8];
    const int wave = t >> 6, lane = t & 63;
    if (lane == 0) {
#pragma unroll
        for (int r = 0; r < 8; ++r) part[wave][r] = acc[r];
    }
    __syncthreads();
    float sq = 0.0f;
    if (t < 8) {
        const float sum = part[0][t] + part[1][t] + part[2][t] + part[3][t];
        const float y = sum * s;
        stf_agent(&vout[row0 + t], y);
        sq = y * y;
    }
    if (wave == 0) {
        for (int off = 32; off > 0; off >>= 1) sq += __shfl_down(sq, off, 64);
        if (lane == 0) atomicAdd(nsq_slot, sq);
    }
    __syncthreads();   // part[] reused next iteration
}

// zero barrier slots + nsq slots (fresh every call -> no cross-call state)
__global__ void pi_init2_kernel(int* __restrict__ cnt, float* __restrict__ ns) {
    const int t = threadIdx.x;
    for (int i = t; i < (ITERS + 1) * CPAD; i += 256) cnt[i] = 0;
    for (int i = t; i < (ITERS + 1) * NSLOT * SPAD; i += 256) ns[i] = 0.0f;
}

// =========================== persistent kernel ==============================
// 1024 blocks x 256 threads, 8 rows/block. Plane: block-private, normal
// cached access. v-buffers: RENAMED per iteration (51 buffers) so readers'
// caches can never hold a stale line -> normal cached float4 loads are safe.
// Only v-writes/nsq/cnt touch the coherence point (tiny).
__global__ __launch_bounds__(256, 4) void pi_persist_kernel(
        const float4* __restrict__ M4,
        __half* __restrict__ plane,
        float* __restrict__ V,      // 51 buffers of N floats: V + k*N
        float* __restrict__ NS,     // nsq slots: NS + k*NSLOT*SPAD + s*SPAD
        int* __restrict__ cnt,
        float* __restrict__ out) {
    const int t = threadIdx.x;
    const int row0 = blockIdx.x * ROWS;
    const int myslot = blockIdx.x & (NSLOT - 1);
    __shared__ float snorm;

    // ---- iter 1: v1 = M @ ones (fp32), convert to fp16 plane (private) ----
    {
        uint2* hp2 = (uint2*)plane;            // row stride 2048 uint2
        float acc[8];
#pragma unroll
        for (int r = 0; r < 8; ++r) acc[r] = 0.0f;
        for (int c = 0; c < 8; ++c) {          // 8 chunks x 256 float4
            const int idx = c * 256 + t;
#pragma unroll
            for (int r = 0; r < 8; ++r) {
                const size_t off = (size_t)(row0 + r) * 2048 + idx;
                const float4 m = M4[off];
                acc[r] += m.x + m.y + m.z + m.w;
                uint2 o;
                o.x = pack2h(m.x, m.y);
                o.y = pack2h(m.z, m.w);
                hp2[off] = o;
            }
        }
        epi8(acc, t, row0, 1.0f, V + 1 * N,
             NS + 1 * NSLOT * SPAD + myslot * SPAD);
    }
    gbar(cnt, 1);

    // ---- iters 2..50: fp16 gemv, cached vin (renamed buffer) ----
    const uint4* h4 = (const uint4*)plane;     // row stride 1024 uint4
    for (int k = 2; k <= ITERS; ++k) {
        // leader sums the 8 nsq slots of iter k-1, broadcasts via LDS
        if (t == 0) {
            float ss = 0.0f;
            const float* base = NS + (size_t)(k - 1) * NSLOT * SPAD;
#pragma unroll
            for (int sl = 0; sl < NSLOT; ++sl) ss += ldf_agent(base + sl * SPAD);
            snorm = ss;
        }
        __syncthreads();
        const float s = rsqrtf(snorm);

        const float4* vin4 = (const float4*)(V + (size_t)(k - 1) * N);
        float acc[8];
#pragma unroll
        for (int r = 0; r < 8; ++r) acc[r] = 0.0f;
        for (int c = 0; c < 4; ++c) {          // 4 chunks x 256 uint4/row
            const int idx = c * 256 + t;
            const float4 va = vin4[2 * idx];
            const float4 vb = vin4[2 * idx + 1];
#pragma unroll
            for (int r = 0; r < 8; ++r) {
                const uint4 h = h4[(size_t)(row0 + r) * 1024 + idx];
                const float2 f0 = h2f(h.x);
                const float2 f1 = h2f(h.y);
                const float2 f2 = h2f(h.z);
                const float2 f3 = h2f(h.w);
                acc[r] += f0.x * va.x + f0.y * va.y + f1.x * va.z +
                          f1.y * va.w + f2.x * vb.x + f2.y * vb.y +
                          f3.x * vb.z + f3.y * vb.w;
            }
        }
        epi8(acc, t, row0, s, V + (size_t)k * N,
             NS + (size_t)k * NSLOT * SPAD + myslot * SPAD);
        gbar(cnt, k);
    }

    // ---- final: out = v50 / ||v50|| ----
    if (t == 0) {
        float ss = 0.0f;
        const float* base = NS + (size_t)ITERS * NSLOT * SPAD;
#pragma unroll
        for (int sl = 0; sl < NSLOT; ++sl) ss += ldf_agent(base + sl * SPAD);
        snorm = ss;
    }
    __syncthreads();
    const float s = rsqrtf(snorm);
    if (t < ROWS) out[row0 + t] = ldf_agent(V + (size_t)ITERS * N + row0 + t) * s;
}

// ============================ fallback (fp32) ================================
__global__ void pi_init_kernel(float* __restrict__ bufA, float* __restrict__ nsq) {
    int i = blockIdx.x * blockDim.x + threadIdx.x;
    if (i < N) bufA[i] = 1.0f;
    if (i <= ITERS) nsq[i] = (i == 0) ? 1.0f : 0.0f;
}

__device__ __forceinline__ void pi_epilogue8(float (&acc)[ROWS], int t, int row0,
                                             float s, float* __restrict__ vout,
                                             float* __restrict__ nsq_next) {
#pragma unroll
    for (int r = 0; r < ROWS; ++r) {
        float a = acc[r];
        for (int off = 32; off > 0; off >>= 1) a += __shfl_down(a, off, 64);
        acc[r] = a;
    }
    __shared__ float part[4][ROWS];
    const int wave = t >> 6, lane = t & 63;
    if (lane == 0) {
#pragma unroll
        for (int r = 0; r < ROWS; ++r) part[wave][r] = acc[r];
    }
    __syncthreads();
    float sq = 0.0f;
    if (t < ROWS) {
        const float sum = part[0][t] + part[1][t] + part[2][t] + part[3][t];
        const float y = sum * s;
        vout[row0 + t] = y;
        sq = y * y;
    }
    if (wave == 0) {
        for (int off = 32; off > 0; off >>= 1) sq += __shfl_down(sq, off, 64);
        if (lane == 0) atomicAdd(nsq_next, sq);
    }
}

__global__ __launch_bounds__(256) void pi_gemv_kernel(
        const float4* __restrict__ M4,
        const float4* __restrict__ vin4,
        float* __restrict__ vout,
        const float* __restrict__ nsq_prev,
        float* __restrict__ nsq_next) {
    const int t = threadIdx.x;
    const int row0 = blockIdx.x * ROWS;
    const float s = rsqrtf(*nsq_prev);
    float acc[ROWS];
#pragma unroll
    for (int r = 0; r < ROWS; ++r) acc[r] = 0.0f;
    for (int c = 0; c < 8; ++c) {
        const int idx = c * 256 + t;
        const float4 vv = vin4[idx];
#pragma unroll
        for (int r = 0; r < ROWS; ++r) {
            const float4 m = M4[(size_t)(row0 + r) * 2048 + idx];
            acc[r] += m.x * vv.x + m.y * vv.y + m.z * vv.z + m.w * vv.w;
        }
    }
    pi_epilogue8(acc, t, row0, s, vout, nsq_next);
}

__global__ void pi_scale_kernel(const float* __restrict__ vin,
                                const float* __restrict__ nsq,
                                float* __restrict__ out) {
    int i = blockIdx.x * blockDim.x + threadIdx.x;
    const float s = rsqrtf(*nsq);
    if (i < N) out[i] = vin[i] * s;
}

// ================================= launch ====================================
extern "C" void kernel_launch(void* const* d_in, const int* in_sizes, int n_in,
                              void* d_out, int out_size, void* d_ws, size_t ws_size,
                              hipStream_t stream) {
    const float* M = (const float*)d_in[0];
    float* out = (float*)d_out;

    const size_t H_BYTES = (size_t)N * N * 2;              // 128 MiB plane
    const size_t V_BYTES = (size_t)(ITERS + 1) * N * 4;    // 51 v-buffers
    const size_t NS_BYTES = (size_t)(ITERS + 1) * NSLOT * SPAD * 4;
    const size_t CNT_BYTES = (size_t)(ITERS + 1) * CPAD * 4;
    const bool use2 = (ws_size >= H_BYTES + V_BYTES + NS_BYTES + CNT_BYTES);

    char* ws = (char*)d_ws;
    const float4* M4 = (const float4*)M;

    if (use2) {
        __half* plane = (__half*)ws;
        float* V   = (float*)(ws + H_BYTES);
        float* NS  = V + (size_t)(ITERS + 1) * N;
        int*   cnt = (int*)(NS + (size_t)(ITERS + 1) * NSLOT * SPAD);

        pi_init2_kernel<<<1, 256, 0, stream>>>(cnt, NS);
        pi_persist_kernel<<<NBLK, 256, 0, stream>>>(
            M4, plane, V, NS, cnt, out);
        return;
    }

    // fallback: fp32 multi-kernel path
    float* bufA = (float*)ws;
    float* bufB = bufA + N;
    float* nsq  = bufB + N;
    pi_init_kernel<<<(N + 255) / 256, 256, 0, stream>>>(bufA, nsq);
    for (int k = 1; k <= ITERS; ++k) {
        const float* vin = (k & 1) ? bufA : bufB;
        float* vout      = (k & 1) ? bufB : bufA;
        pi_gemv_kernel<<<N / ROWS, 256, 0, stream>>>(
            M4, (const float4*)vin, vout, nsq + (k - 1), nsq + k);
    }
    pi_scale_kernel<<<(N + 255) / 256, 256, 0, stream>>>(bufA, nsq + ITERS, out);
}

// Round 15
// 1549.781 us; speedup vs baseline: 2.5513x; 2.5513x over previous
//
#include <hip/hip_runtime.h>
#include <hip/hip_fp16.h>

#define N 8192
#define ITERS 50
#define ROWS 8      // fallback path rows/block
#define RPB 16      // persistent rows/block
#define NBLK 512    // 256 CU x 2 blocks/CU, co-resident (launch_bounds(256,2))
#define NGRP 32     // barrier groups
#define GSZ 16      // blocks per group (NGRP*GSZ == NBLK)
#define NSLOT 8     // nsq partial slots
#define PAD 32      // words per slot (128 B line)

typedef unsigned int uint32;

__device__ __forceinline__ uint32 pack2h(float x, float y) {
    __half2 p = __float22half2_rn(make_float2(x, y));
    return *reinterpret_cast<uint32*>(&p);
}
__device__ __forceinline__ float2 h2f(uint32 u) {
    __half2 h = *reinterpret_cast<__half2*>(&u);
    return __half22float2(h);
}

__device__ __forceinline__ float ldf_agent(const float* p) {
    return __hip_atomic_load(p, __ATOMIC_RELAXED, __HIP_MEMORY_SCOPE_AGENT);
}
__device__ __forceinline__ void stf_agent(float* p, float v) {
    __hip_atomic_store(p, v, __ATOMIC_RELAXED, __HIP_MEMORY_SCOPE_AGENT);
}
__device__ __forceinline__ int ldi_agent(const int* p) {
    return __hip_atomic_load(p, __ATOMIC_RELAXED, __HIP_MEMORY_SCOPE_AGENT);
}
__device__ __forceinline__ void addi_agent(int* p) {
    __hip_atomic_fetch_add(p, 1, __ATOMIC_RELAXED, __HIP_MEMORY_SCOPE_AGENT);
}

// nontemporal float4 load via scalar lanes (builtin rejects HIP vector types)
__device__ __forceinline__ float4 ntload4(const float4* p) {
    const float* f = (const float*)p;
    float4 r;
    r.x = __builtin_nontemporal_load(f + 0);
    r.y = __builtin_nontemporal_load(f + 1);
    r.z = __builtin_nontemporal_load(f + 2);
    r.w = __builtin_nontemporal_load(f + 3);
    return r;
}

// hierarchical grid barrier + norm publish. Returns sum of NS[k] slots.
// No cache line is touched by more than 32 requesters.
__device__ __forceinline__ float gbar_pub(
        int k, int g, bool gld, bool rblk, int t,
        float* NS, int* LEAF, int* ROOT, float* RGO, float* GO) {
    __shared__ float sh;
    __syncthreads();                   // drains vmcnt: V/NS writes at CP
    if (t == 0) {
        addi_agent(&LEAF[(k * NGRP + g) * PAD]);
        if (gld) {
            while (ldi_agent(&LEAF[(k * NGRP + g) * PAD]) < GSZ)
                __builtin_amdgcn_s_sleep(2);
            addi_agent(&ROOT[k * PAD]);
        }
        if (rblk) {
            while (ldi_agent(&ROOT[k * PAD]) < NGRP)
                __builtin_amdgcn_s_sleep(2);
            float p0 = ldf_agent(&NS[(k * NSLOT + 0) * PAD]);
            float p1 = ldf_agent(&NS[(k * NSLOT + 1) * PAD]);
            float p2 = ldf_agent(&NS[(k * NSLOT + 2) * PAD]);
            float p3 = ldf_agent(&NS[(k * NSLOT + 3) * PAD]);
            float p4 = ldf_agent(&NS[(k * NSLOT + 4) * PAD]);
            float p5 = ldf_agent(&NS[(k * NSLOT + 5) * PAD]);
            float p6 = ldf_agent(&NS[(k * NSLOT + 6) * PAD]);
            float p7 = ldf_agent(&NS[(k * NSLOT + 7) * PAD]);
            stf_agent(&RGO[k * PAD],
                      ((p0 + p1) + (p2 + p3)) + ((p4 + p5) + (p6 + p7)));
        }
        float val;
        if (gld) {
            do {
                val = ldf_agent(&RGO[k * PAD]);
                if (val != 0.0f) break;
                __builtin_amdgcn_s_sleep(1);
            } while (true);
            stf_agent(&GO[(k * NGRP + g) * PAD], val);
        } else {
            do {
                val = ldf_agent(&GO[(k * NGRP + g) * PAD]);
                if (val != 0.0f) break;
                __builtin_amdgcn_s_sleep(1);
            } while (true);
        }
        sh = val;
    }
    __syncthreads();
    return sh;
}

// split epilogue (r12 shape): waves 0-1 rows 0-7, waves 2-3 rows 8-15.
__device__ __forceinline__ void epi_split(float (&acc)[8], int t, int row0,
                                          float s, float* vout, float* nslot) {
#pragma unroll
    for (int r = 0; r < 8; ++r) {
        float a = acc[r];
        for (int off = 32; off > 0; off >>= 1) a += __shfl_down(a, off, 64);
        acc[r] = a;
    }
    __shared__ float part[4][8];
    const int wave = t >> 6, lane = t & 63;
    if (lane == 0) {
#pragma unroll
        for (int r = 0; r < 8; ++r) part[wave][r] = acc[r];
    }
    __syncthreads();
    float sq = 0.0f;
    if (t < RPB) {
        const float sum = (t < 8) ? part[0][t] + part[1][t]
                                  : part[2][t - 8] + part[3][t - 8];
        const float y = sum * s;
        stf_agent(&vout[row0 + t], y);
        sq = y * y;
    }
    if (wave == 0) {
        for (int off = 32; off > 0; off >>= 1) sq += __shfl_down(sq, off, 64);
        if (lane == 0) atomicAdd(nslot, sq);
    }
    __syncthreads();
}

// zero the whole sync region (fresh every call)
__global__ void pi_initz_kernel(float* __restrict__ z, int nwords) {
    for (int i = blockIdx.x * blockDim.x + threadIdx.x; i < nwords;
         i += gridDim.x * blockDim.x)
        z[i] = 0.0f;
}

// =========================== persistent kernel ==============================
__global__ __launch_bounds__(256, 2) void pi_persist_kernel(
        const float4* __restrict__ M4,
        __half* __restrict__ plane,
        float* __restrict__ V,       // 51 x N floats
        float* __restrict__ NS,      // (k*NSLOT+s)*PAD
        int* __restrict__ LEAF,      // (k*NGRP+g)*PAD
        int* __restrict__ ROOT,      // k*PAD
        float* __restrict__ RGO,     // k*PAD
        float* __restrict__ GO,      // (k*NGRP+g)*PAD
        float* __restrict__ out) {
    const int t = threadIdx.x;
    const int col = t & 127;
    const int row0 = blockIdx.x * RPB;
    const int rbase = row0 + (t >> 7) * 8;
    const int g = blockIdx.x >> 4;
    const bool gld = (blockIdx.x & 15) == 0;
    const bool rblk = (blockIdx.x == 0);
    const int myslot = blockIdx.x & (NSLOT - 1);

    // ---- iter 1: v1 = M @ ones (fp32, nontemporal), convert to fp16 ----
    {
        uint2* hp2 = (uint2*)plane;            // row stride 2048 uint2
        float acc[8];
#pragma unroll
        for (int r = 0; r < 8; ++r) acc[r] = 0.0f;
        for (int c = 0; c < 16; ++c) {
            const int ci = c * 128 + col;
#pragma unroll
            for (int r = 0; r < 8; ++r) {
                const size_t off = (size_t)(rbase + r) * 2048 + ci;
                const float4 m = ntload4(&M4[off]);
                acc[r] += m.x + m.y + m.z + m.w;
                uint2 o;
                o.x = pack2h(m.x, m.y);
                o.y = pack2h(m.z, m.w);
                hp2[off] = o;
            }
        }
        epi_split(acc, t, row0, 1.0f, V + N,
                  NS + (1 * NSLOT + myslot) * PAD);
    }
    float nrm = gbar_pub(1, g, gld, rblk, t, NS, LEAF, ROOT, RGO, GO);

    // ---- iters 2..50: fp16 gemv, cached vin (renamed buffers) ----
    const uint4* h4 = (const uint4*)plane;     // row stride 1024 uint4
    for (int k = 2; k <= ITERS; ++k) {
        const float s = rsqrtf(nrm);
        const float4* vin4 = (const float4*)(V + (size_t)(k - 1) * N);
        float acc[8];
#pragma unroll
        for (int r = 0; r < 8; ++r) acc[r] = 0.0f;
        for (int c = 0; c < 8; ++c) {          // 8 chunks x 128 uint4/row
            const int ci = c * 128 + col;
            const float4 va = vin4[2 * ci];
            const float4 vb = vin4[2 * ci + 1];
#pragma unroll
            for (int r = 0; r < 8; ++r) {
                const uint4 h = h4[(size_t)(rbase + r) * 1024 + ci];
                const float2 f0 = h2f(h.x);
                const float2 f1 = h2f(h.y);
                const float2 f2 = h2f(h.z);
                const float2 f3 = h2f(h.w);
                acc[r] += f0.x * va.x + f0.y * va.y + f1.x * va.z +
                          f1.y * va.w + f2.x * vb.x + f2.y * vb.y +
                          f3.x * vb.z + f3.y * vb.w;
            }
        }
        epi_split(acc, t, row0, s, V + (size_t)k * N,
                  NS + ((size_t)k * NSLOT + myslot) * PAD);
        nrm = gbar_pub(k, g, gld, rblk, t, NS, LEAF, ROOT, RGO, GO);
    }

    // ---- final: out = v50 * rsqrt(norm50) ----
    const float s = rsqrtf(nrm);
    if (t < RPB) out[row0 + t] = ldf_agent(V + (size_t)ITERS * N + row0 + t) * s;
}

// ============================ fallback (fp32) ================================
__global__ void pi_init_kernel(float* __restrict__ bufA, float* __restrict__ nsq) {
    int i = blockIdx.x * blockDim.x + threadIdx.x;
    if (i < N) bufA[i] = 1.0f;
    if (i <= ITERS) nsq[i] = (i == 0) ? 1.0f : 0.0f;
}

__device__ __forceinline__ void pi_epilogue8(float (&acc)[ROWS], int t, int row0,
                                             float s, float* __restrict__ vout,
                                             float* __restrict__ nsq_next) {
#pragma unroll
    for (int r = 0; r < ROWS; ++r) {
        float a = acc[r];
        for (int off = 32; off > 0; off >>= 1) a += __shfl_down(a, off, 64);
        acc[r] = a;
    }
    __shared__ float part[4][ROWS];
    const int wave = t >> 6, lane = t & 63;
    if (lane == 0) {
#pragma unroll
        for (int r = 0; r < ROWS; ++r) part[wave][r] = acc[r];
    }
    __syncthreads();
    float sq = 0.0f;
    if (t < ROWS) {
        const float sum = part[0][t] + part[1][t] + part[2][t] + part[3][t];
        const float y = sum * s;
        vout[row0 + t] = y;
        sq = y * y;
    }
    if (wave == 0) {
        for (int off = 32; off > 0; off >>= 1) sq += __shfl_down(sq, off, 64);
        if (lane == 0) atomicAdd(nsq_next, sq);
    }
}

__global__ __launch_bounds__(256) void pi_gemv_kernel(
        const float4* __restrict__ M4,
        const float4* __restrict__ vin4,
        float* __restrict__ vout,
        const float* __restrict__ nsq_prev,
        float* __restrict__ nsq_next) {
    const int t = threadIdx.x;
    const int row0 = blockIdx.x * ROWS;
    const float s = rsqrtf(*nsq_prev);
    float acc[ROWS];
#pragma unroll
    for (int r = 0; r < ROWS; ++r) acc[r] = 0.0f;
    for (int c = 0; c < 8; ++c) {
        const int idx = c * 256 + t;
        const float4 vv = vin4[idx];
#pragma unroll
        for (int r = 0; r < ROWS; ++r) {
            const float4 m = M4[(size_t)(row0 + r) * 2048 + idx];
            acc[r] += m.x * vv.x + m.y * vv.y + m.z * vv.z + m.w * vv.w;
        }
    }
    pi_epilogue8(acc, t, row0, s, vout, nsq_next);
}

__global__ void pi_scale_kernel(const float* __restrict__ vin,
                                const float* __restrict__ nsq,
                                float* __restrict__ out) {
    int i = blockIdx.x * blockDim.x + threadIdx.x;
    const float s = rsqrtf(*nsq);
    if (i < N) out[i] = vin[i] * s;
}

// ================================= launch ====================================
extern "C" void kernel_launch(void* const* d_in, const int* in_sizes, int n_in,
                              void* d_out, int out_size, void* d_ws, size_t ws_size,
                              hipStream_t stream) {
    const float* M = (const float*)d_in[0];
    float* out = (float*)d_out;

    const int K1 = ITERS + 1;
    const size_t H_BYTES = (size_t)N * N * 2;            // 128 MiB plane
    const size_t V_W   = (size_t)K1 * N;                 // v buffers (words)
    const size_t NS_W  = (size_t)K1 * NSLOT * PAD;
    const size_t LF_W  = (size_t)K1 * NGRP * PAD;
    const size_t RT_W  = (size_t)K1 * PAD;
    const size_t RG_W  = (size_t)K1 * PAD;
    const size_t GO_W  = (size_t)K1 * NGRP * PAD;
    const size_t SYNC_W = NS_W + LF_W + RT_W + RG_W + GO_W;
    const bool use2 = (ws_size >= H_BYTES + (V_W + SYNC_W) * 4);

    char* ws = (char*)d_ws;
    const float4* M4 = (const float4*)M;

    if (use2) {
        __half* plane = (__half*)ws;
        float* V    = (float*)(ws + H_BYTES);
        float* NS   = V + V_W;
        int*   LEAF = (int*)(NS + NS_W);
        int*   ROOT = (int*)(NS + NS_W + LF_W);
        float* RGO  = NS + NS_W + LF_W + RT_W;
        float* GO   = NS + NS_W + LF_W + RT_W + RG_W;

        pi_initz_kernel<<<64, 256, 0, stream>>>(NS, (int)SYNC_W);
        pi_persist_kernel<<<NBLK, 256, 0, stream>>>(
            M4, plane, V, NS, LEAF, ROOT, RGO, GO, out);
        return;
    }

    // fallback: fp32 multi-kernel path
    float* bufA = (float*)ws;
    float* bufB = bufA + N;
    float* nsq  = bufB + N;
    pi_init_kernel<<<(N + 255) / 256, 256, 0, stream>>>(bufA, nsq);
    for (int k = 1; k <= ITERS; ++k) {
        const float* vin = (k & 1) ? bufA : bufB;
        float* vout      = (k & 1) ? bufB : bufA;
        pi_gemv_kernel<<<N / ROWS, 256, 0, stream>>>(
            M4, (const float4*)vin, vout, nsq + (k - 1), nsq + k);
    }
    pi_scale_kernel<<<(N + 255) / 256, 256, 0, stream>>>(bufA, nsq + ITERS, out);
}